// Round 4
// baseline (205.372 us; speedup 1.0000x reference)
//
#include <hip/hip_runtime.h>

// B=16, C=128, H=W=64, N=4096 (zigzag p-space), M=1024, CQ=16, CV=64.
// ws (shorts): qT[16][4096][16] @0, kT[16][1024][16] @1048576,
//              vO[16][64][1024] @1310720.  Total 4.7 MB.

#define LOG2E 1.4426950408889634f

typedef __attribute__((ext_vector_type(8)))  short bf16x8;
typedef __attribute__((ext_vector_type(16))) float f32x16;

static __device__ __forceinline__ unsigned cvt_pk_bf16(float a, float b) {
  unsigned r;
  asm("v_cvt_pk_bf16_f32 %0, %1, %2" : "=v"(r) : "v"(a), "v"(b));
  return r;
}
static __device__ __forceinline__ void perm32swap(unsigned& a, unsigned& b) {
  asm volatile("v_permlane32_swap_b32 %0, %1" : "+v"(a), "+v"(b));
}
static __device__ __forceinline__ float fexp2(float x) {
  float r; asm("v_exp_f32 %0, %1" : "=v"(r) : "v"(x)); return r;
}
static __device__ __forceinline__ bf16x8 pack4(unsigned u0, unsigned u1,
                                               unsigned u2, unsigned u3) {
  union { bf16x8 v; unsigned u[4]; } r;
  r.u[0] = u0; r.u[1] = u1; r.u[2] = u2; r.u[3] = u3;
  return r.v;
}
static __device__ __forceinline__ short f2bf(float f) {   // RTNE
  unsigned u = __float_as_uint(f);
  u = (u + 0x7FFFu + ((u >> 16) & 1u)) >> 16;
  return (short)u;
}
// w-row A-fragment: lane=row holds 8 consecutive c as bf16
#define LOADW(PTR, C0)                                                      \
    ({ const float* r_ = (PTR) + (C0) + hi * 8;                             \
       float4 f0 = *(const float4*)r_, f1 = *(const float4*)(r_ + 4);       \
       pack4(cvt_pk_bf16(f0.x, f0.y), cvt_pk_bf16(f0.z, f0.w),              \
             cvt_pk_bf16(f1.x, f1.y), cvt_pk_bf16(f1.z, f1.w)); })

// ---------------------------------------------------------------------------
// Kernel 1: fused transpose + q/k/v proj + pool. D[ch][p] = mfma(W, xfrag);
// x read in native layout as the B operand (lane = p column, 8 scalar c
// loads). Pool across lane quads via shfl_xor. q/k converted to B-frag /
// A-frag-ready [row][16] layouts in-register (cvt_pk + permlane32_swap);
// V transposed to [c2][m] via 4 KB LDS.
// ---------------------------------------------------------------------------
__global__ __launch_bounds__(256) void proj_kernel(
    const float* __restrict__ x, const float* __restrict__ wq,
    const float* __restrict__ wk, const float* __restrict__ wv,
    short* __restrict__ qT, short* __restrict__ kT, short* __restrict__ vO)
{
  __shared__ short v_s[64 * 32];

  const int b = blockIdx.y, t = threadIdx.x;
  const int wid = t >> 6, lane = t & 63;
  const int l31 = lane & 31, hi = lane >> 5;
  const int p = blockIdx.x * 128 + wid * 32 + l31;
  const int q2 = p >> 2, rr = p & 3;
  const int nsp = ((((q2 >> 5) << 1) | (rr >> 1)) << 6) | (((q2 & 31) << 1) | (rr & 1));

  // ---- pass 1: x B-fragments (64 scalar loads, independent) ----
  const float* xc = x + (size_t)b * 128 * 4096 + (size_t)hi * 8 * 4096 + nsp;
  bf16x8 xf[8];
  #pragma unroll
  for (int cc = 0; cc < 8; ++cc) {
    float f[8];
    #pragma unroll
    for (int j = 0; j < 8; ++j) f[j] = xc[(size_t)(cc * 16 + j) * 4096];
    xf[cc] = pack4(cvt_pk_bf16(f[0], f[1]), cvt_pk_bf16(f[2], f[3]),
                   cvt_pk_bf16(f[4], f[5]), cvt_pk_bf16(f[6], f[7]));
  }

  // ---- pass 2: MFMA over K=128 ----
  const float* w0p = (l31 < 16) ? (wq + l31 * 128) : (wk + (l31 - 16) * 128);
  const float* w1p = wv + l31 * 128;
  const float* w2p = wv + (32 + l31) * 128;

  f32x16 acc0, acc1, acc2;
  #pragma unroll
  for (int j = 0; j < 16; ++j) { acc0[j] = 0.f; acc1[j] = 0.f; acc2[j] = 0.f; }

  #pragma unroll
  for (int cc = 0; cc < 8; ++cc) {
    const int c0 = cc * 16;
    bf16x8 a0 = LOADW(w0p, c0), a1 = LOADW(w1p, c0), a2 = LOADW(w2p, c0);
    acc0 = __builtin_amdgcn_mfma_f32_32x32x16_bf16(a0, xf[cc], acc0, 0, 0, 0);
    acc1 = __builtin_amdgcn_mfma_f32_32x32x16_bf16(a1, xf[cc], acc1, 0, 0, 0);
    acc2 = __builtin_amdgcn_mfma_f32_32x32x16_bf16(a2, xf[cc], acc2, 0, 0, 0);
  }

  // ---- q: rows 0..15 (regs r0..7), scaled by log2e, -> B-frag layout ----
  {
    unsigned u0 = cvt_pk_bf16(acc0[0] * LOG2E, acc0[1] * LOG2E);
    unsigned u1 = cvt_pk_bf16(acc0[2] * LOG2E, acc0[3] * LOG2E);
    unsigned u2 = cvt_pk_bf16(acc0[4] * LOG2E, acc0[5] * LOG2E);
    unsigned u3 = cvt_pk_bf16(acc0[6] * LOG2E, acc0[7] * LOG2E);
    perm32swap(u0, u2); perm32swap(u1, u3);
    *(bf16x8*)(qT + ((size_t)b * 4096 + p) * 16 + hi * 8) = pack4(u0, u1, u2, u3);
  }

  // ---- k: rows 16..31 (regs r8..15), pool across lane quads ----
  {
    float pk[8];
    #pragma unroll
    for (int r = 8; r < 16; ++r) {
      float m = acc0[r];
      m = fmaxf(m, __shfl_xor(m, 1));
      m = fmaxf(m, __shfl_xor(m, 2));
      pk[r - 8] = m;
    }
    unsigned u0 = cvt_pk_bf16(pk[0], pk[1]), u1 = cvt_pk_bf16(pk[2], pk[3]);
    unsigned u2 = cvt_pk_bf16(pk[4], pk[5]), u3 = cvt_pk_bf16(pk[6], pk[7]);
    perm32swap(u0, u2); perm32swap(u1, u3);
    if ((l31 & 3) == 0)
      *(bf16x8*)(kT + ((size_t)b * 1024 + (p >> 2)) * 16 + hi * 8) =
          pack4(u0, u1, u2, u3);
  }

  // ---- v: pool both tiles, transpose to [c2][m] via LDS ----
  {
    float pv1[16], pv2[16];
    #pragma unroll
    for (int r = 0; r < 16; ++r) {
      float m1 = acc1[r], m2 = acc2[r];
      m1 = fmaxf(m1, __shfl_xor(m1, 1)); m1 = fmaxf(m1, __shfl_xor(m1, 2));
      m2 = fmaxf(m2, __shfl_xor(m2, 1)); m2 = fmaxf(m2, __shfl_xor(m2, 2));
      pv1[r] = m1; pv2[r] = m2;
    }
    if ((l31 & 3) == 0) {
      const int q2l = wid * 8 + (l31 >> 2);
      #pragma unroll
      for (int r = 0; r < 16; ++r) {
        const int c2 = (r & 3) + 8 * (r >> 2) + 4 * hi;
        v_s[c2 * 32 + q2l]        = f2bf(pv1[r]);
        v_s[(32 + c2) * 32 + q2l] = f2bf(pv2[r]);
      }
    }
  }
  __syncthreads();
  {
    const int c2 = t >> 2, off = (t & 3) * 8;
    *(bf16x8*)(vO + ((size_t)b * 64 + c2) * 1024 + blockIdx.x * 32 + off) =
        *(const bf16x8*)&v_s[c2 * 32 + off];
  }
}

// ---------------------------------------------------------------------------
// Kernel 2: split-M flash attention + wo + residual. Block = 32 q, 4 waves
// each owning 8 M-tiles; partials combined via ds_add_f32 in LDS; epilogue:
// wave w computes wo rows [w*32, w*32+32) with o B-frag read from LDS.
// ---------------------------------------------------------------------------
__global__ __launch_bounds__(256) void attn_kernel(
    const short* __restrict__ qT, const short* __restrict__ kT,
    const short* __restrict__ vO, const float* __restrict__ wo,
    const float* __restrict__ x, const float* __restrict__ gamma,
    float* __restrict__ out)
{
  __shared__ float osum[64 * 32];
  __shared__ float lsum[32];

  const int b = blockIdx.y, t = threadIdx.x;
  const int wid = t >> 6, lane = t & 63;
  const int l31 = lane & 31, hi = lane >> 5;
  const int p = blockIdx.x * 32 + l31;

  #pragma unroll
  for (int i = t; i < 64 * 32; i += 256) osum[i] = 0.f;
  if (t < 32) lsum[t] = 0.f;
  __syncthreads();

  const short* kTb = kT + (size_t)b * 1024 * 16;
  const short* vb  = vO + (size_t)b * 64 * 1024;
  const bf16x8 qf = *(const bf16x8*)(qT + ((size_t)b * 4096 + p) * 16 + hi * 8);

  f32x16 z, o0, o1;
  #pragma unroll
  for (int j = 0; j < 16; ++j) { z[j] = 0.f; o0[j] = 0.f; o1[j] = 0.f; }
  float l = 0.f;

  #pragma unroll 2
  for (int mt = wid * 8; mt < wid * 8 + 8; ++mt) {
    const int m0 = mt * 32;
    const bf16x8 kf = *(const bf16x8*)(kTb + (size_t)(m0 + l31) * 16 + hi * 8);
    const size_t vr0 = (size_t)l31 * 1024 + m0 + hi * 8;
    const size_t vr1 = (size_t)(32 + l31) * 1024 + m0 + hi * 8;
    const bf16x8 v00 = *(const bf16x8*)(vb + vr0);
    const bf16x8 v01 = *(const bf16x8*)(vb + vr0 + 16);
    const bf16x8 v10 = *(const bf16x8*)(vb + vr1);
    const bf16x8 v11 = *(const bf16x8*)(vb + vr1 + 16);

    f32x16 s = __builtin_amdgcn_mfma_f32_32x32x16_bf16(kf, qf, z, 0, 0, 0);

    float pe[16];
    #pragma unroll
    for (int j = 0; j < 16; ++j) pe[j] = fexp2(s[j]);
    l += ((pe[0] + pe[1]) + (pe[2] + pe[3])) + ((pe[4] + pe[5]) + (pe[6] + pe[7]))
       + ((pe[8] + pe[9]) + (pe[10] + pe[11])) + ((pe[12] + pe[13]) + (pe[14] + pe[15]));

    unsigned a0 = cvt_pk_bf16(pe[0], pe[1]),  a1 = cvt_pk_bf16(pe[2], pe[3]);
    unsigned a2 = cvt_pk_bf16(pe[4], pe[5]),  a3 = cvt_pk_bf16(pe[6], pe[7]);
    perm32swap(a0, a2); perm32swap(a1, a3);
    const bf16x8 P0 = pack4(a0, a1, a2, a3);
    unsigned c0 = cvt_pk_bf16(pe[8], pe[9]),   c1 = cvt_pk_bf16(pe[10], pe[11]);
    unsigned c2 = cvt_pk_bf16(pe[12], pe[13]), c3 = cvt_pk_bf16(pe[14], pe[15]);
    perm32swap(c0, c2); perm32swap(c1, c3);
    const bf16x8 P1 = pack4(c0, c1, c2, c3);

    o0 = __builtin_amdgcn_mfma_f32_32x32x16_bf16(v00, P0, o0, 0, 0, 0);
    o0 = __builtin_amdgcn_mfma_f32_32x32x16_bf16(v01, P1, o0, 0, 0, 0);
    o1 = __builtin_amdgcn_mfma_f32_32x32x16_bf16(v10, P0, o1, 0, 0, 0);
    o1 = __builtin_amdgcn_mfma_f32_32x32x16_bf16(v11, P1, o1, 0, 0, 0);
  }

  // combine partials
  atomicAdd(&lsum[l31], l);
  #pragma unroll
  for (int r = 0; r < 16; ++r) {
    const int c2r = (r & 3) + 8 * (r >> 2) + 4 * hi;
    atomicAdd(&osum[c2r * 32 + l31], o0[r]);
    atomicAdd(&osum[(32 + c2r) * 32 + l31], o1[r]);
  }
  __syncthreads();

  // wo epilogue: wave wid -> out rows [wid*32, wid*32+32)
  const float inv = 1.0f / lsum[l31];
  const float g = gamma[0];

  f32x16 acc;
  #pragma unroll
  for (int j = 0; j < 16; ++j) acc[j] = 0.f;

  #pragma unroll
  for (int ck = 0; ck < 4; ++ck) {
    float f[8];
    #pragma unroll
    for (int j = 0; j < 8; ++j)
      f[j] = osum[(ck * 16 + hi * 8 + j) * 32 + l31] * inv;
    const bf16x8 ofr = pack4(cvt_pk_bf16(f[0], f[1]), cvt_pk_bf16(f[2], f[3]),
                             cvt_pk_bf16(f[4], f[5]), cvt_pk_bf16(f[6], f[7]));
    const bf16x8 wf = LOADW(wo + (size_t)(wid * 32 + l31) * 64, ck * 16);
    acc = __builtin_amdgcn_mfma_f32_32x32x16_bf16(wf, ofr, acc, 0, 0, 0);
  }

  const int q2 = p >> 2, rr = p & 3;
  const int nsp = ((((q2 >> 5) << 1) | (rr >> 1)) << 6) | (((q2 & 31) << 1) | (rr & 1));
  const float* xb = x + (size_t)b * 128 * 4096 + nsp;
  float* ob = out + (size_t)b * 128 * 4096 + nsp;

  #pragma unroll
  for (int r = 0; r < 16; ++r) {
    const int co = wid * 32 + (r & 3) + 8 * (r >> 2) + 4 * hi;
    ob[(size_t)co * 4096] = g * acc[r] + xb[(size_t)co * 4096];
  }
}

extern "C" void kernel_launch(void* const* d_in, const int* in_sizes, int n_in,
                              void* d_out, int out_size, void* d_ws, size_t ws_size,
                              hipStream_t stream) {
  const float* x     = (const float*)d_in[0];
  const float* wq    = (const float*)d_in[1];
  const float* wk    = (const float*)d_in[2];
  const float* wv    = (const float*)d_in[3];
  const float* wo    = (const float*)d_in[4];
  const float* gamma = (const float*)d_in[5];
  float* out = (float*)d_out;

  short* ws = (short*)d_ws;
  short* qT = ws;                 // 16*4096*16
  short* kT = ws + 1048576;       // 16*1024*16
  short* vO = ws + 1310720;       // 16*64*1024

  proj_kernel<<<dim3(32, 16), 256, 0, stream>>>(x, wq, wk, wv, qT, kT, vO);
  attn_kernel<<<dim3(128, 16), 256, 0, stream>>>(qT, kT, vO, wo, x, gamma, out);
}

// Round 6
// 137.925 us; speedup vs baseline: 1.4890x; 1.4890x over previous
//
#include <hip/hip_runtime.h>

// B=16, C=128, H=W=64, N=4096 (zigzag p-space), M=1024, CQ=16, CV=64.
// ws (shorts): qT[16][4096][16] @0, kT[16][1024][16] @1048576,
//              vO[16][64][1024] @1310720.  Total 4.7 MB.

#define LOG2E 1.4426950408889634f

typedef __attribute__((ext_vector_type(8)))  short bf16x8;
typedef __attribute__((ext_vector_type(16))) float f32x16;
typedef unsigned long long ull;

static __device__ __forceinline__ unsigned cvt_pk_bf16(float a, float b) {
  unsigned r;
  asm("v_cvt_pk_bf16_f32 %0, %1, %2" : "=v"(r) : "v"(a), "v"(b));
  return r;
}
static __device__ __forceinline__ void perm32swap(unsigned& a, unsigned& b) {
  asm volatile("v_permlane32_swap_b32 %0, %1" : "+v"(a), "+v"(b));
}
static __device__ __forceinline__ float fexp2(float x) {
  float r; asm("v_exp_f32 %0, %1" : "=v"(r) : "v"(x)); return r;
}
static __device__ __forceinline__ bf16x8 pack4(unsigned u0, unsigned u1,
                                               unsigned u2, unsigned u3) {
  union { bf16x8 v; unsigned u[4]; } r;
  r.u[0] = u0; r.u[1] = u1; r.u[2] = u2; r.u[3] = u3;
  return r.v;
}
static __device__ __forceinline__ bf16x8 pack2ull(ull a, ull b) {
  union { bf16x8 v; ull u[2]; } r;
  r.u[0] = a; r.u[1] = b;
  return r.v;
}
static __device__ __forceinline__ short f2bf(float f) {   // RTNE
  unsigned u = __float_as_uint(f);
  u = (u + 0x7FFFu + ((u >> 16) & 1u)) >> 16;
  return (short)u;
}

// ---------------------------------------------------------------------------
// Kernel 1: fused transpose + q/k/v proj + pool. D[ch][p] = mfma(W, xfrag).
// Weights staged ONCE per block into LDS (padded stride 136 shorts -> aligned
// b128 frag reads) -- kills the per-thread global weight gathers (32
// sectors/instr) that made R3/R4 proj latency-bound.
// x read in native layout as B operand (64 scalar loads, issued up front).
// ---------------------------------------------------------------------------
#define WSTRIDE 136   // shorts; 272B row stride, 16B-aligned frag reads

__global__ __launch_bounds__(256) void proj_kernel(
    const float* __restrict__ x, const float* __restrict__ wq,
    const float* __restrict__ wk, const float* __restrict__ wv,
    short* __restrict__ qT, short* __restrict__ kT, short* __restrict__ vO)
{
  __shared__ short w_s[96 * WSTRIDE];   // 26 KB: rows 0-15 wq, 16-31 wk, 32-95 wv
  __shared__ short v_s[64 * 32];

  const int b = blockIdx.y, t = threadIdx.x;
  const int wid = t >> 6, lane = t & 63;
  const int l31 = lane & 31, hi = lane >> 5;
  const int p = blockIdx.x * 128 + wid * 32 + l31;
  const int q2 = p >> 2, rr = p & 3;
  const int nsp = ((((q2 >> 5) << 1) | (rr >> 1)) << 6) | (((q2 & 31) << 1) | (rr & 1));

  // ---- x loads: 64 independent scalar fp32 loads, issued early ----
  const float* xc = x + (size_t)b * 128 * 4096 + (size_t)hi * 8 * 4096 + nsp;
  float xv[8][8];
  #pragma unroll
  for (int cc = 0; cc < 8; ++cc)
    #pragma unroll
    for (int j = 0; j < 8; ++j)
      xv[cc][j] = xc[(size_t)(cc * 16 + j) * 4096];

  // ---- stage weights -> LDS (coalesced fp32 reads, cvt to bf16) ----
  #pragma unroll
  for (int kk = 0; kk < 12; ++kk) {
    const int idx = t + kk * 256;          // 0..3071
    const int row = idx >> 5, c4 = (idx & 31) << 2;
    const float* src = (row < 16) ? (wq + row * 128 + c4)
                     : (row < 32) ? (wk + (row - 16) * 128 + c4)
                                  : (wv + (row - 32) * 128 + c4);
    const float4 f = *(const float4*)src;
    const ull v = ((ull)cvt_pk_bf16(f.z, f.w) << 32) | (ull)cvt_pk_bf16(f.x, f.y);
    *(ull*)&w_s[row * WSTRIDE + c4] = v;
  }
  __syncthreads();

  // ---- pack x B-fragments ----
  bf16x8 xf[8];
  #pragma unroll
  for (int cc = 0; cc < 8; ++cc)
    xf[cc] = pack4(cvt_pk_bf16(xv[cc][0], xv[cc][1]), cvt_pk_bf16(xv[cc][2], xv[cc][3]),
                   cvt_pk_bf16(xv[cc][4], xv[cc][5]), cvt_pk_bf16(xv[cc][6], xv[cc][7]));

  // ---- MFMA over K=128; A-frags from LDS ----
  f32x16 acc0, acc1, acc2;
  #pragma unroll
  for (int j = 0; j < 16; ++j) { acc0[j] = 0.f; acc1[j] = 0.f; acc2[j] = 0.f; }

  #pragma unroll
  for (int cc = 0; cc < 8; ++cc) {
    const int off = cc * 16 + hi * 8;
    const bf16x8 a0 = *(const bf16x8*)&w_s[l31 * WSTRIDE + off];        // q|k rows
    const bf16x8 a1 = *(const bf16x8*)&w_s[(32 + l31) * WSTRIDE + off]; // wv 0..31
    const bf16x8 a2 = *(const bf16x8*)&w_s[(64 + l31) * WSTRIDE + off]; // wv 32..63
    acc0 = __builtin_amdgcn_mfma_f32_32x32x16_bf16(a0, xf[cc], acc0, 0, 0, 0);
    acc1 = __builtin_amdgcn_mfma_f32_32x32x16_bf16(a1, xf[cc], acc1, 0, 0, 0);
    acc2 = __builtin_amdgcn_mfma_f32_32x32x16_bf16(a2, xf[cc], acc2, 0, 0, 0);
  }

  // ---- q: rows 0..15 (regs r0..7), scaled by log2e, -> B-frag layout ----
  {
    unsigned u0 = cvt_pk_bf16(acc0[0] * LOG2E, acc0[1] * LOG2E);
    unsigned u1 = cvt_pk_bf16(acc0[2] * LOG2E, acc0[3] * LOG2E);
    unsigned u2 = cvt_pk_bf16(acc0[4] * LOG2E, acc0[5] * LOG2E);
    unsigned u3 = cvt_pk_bf16(acc0[6] * LOG2E, acc0[7] * LOG2E);
    perm32swap(u0, u2); perm32swap(u1, u3);
    *(bf16x8*)(qT + ((size_t)b * 4096 + p) * 16 + hi * 8) = pack4(u0, u1, u2, u3);
  }

  // ---- k: rows 16..31 (regs r8..15), pool across lane quads ----
  {
    float pk[8];
    #pragma unroll
    for (int r = 8; r < 16; ++r) {
      float m = acc0[r];
      m = fmaxf(m, __shfl_xor(m, 1));
      m = fmaxf(m, __shfl_xor(m, 2));
      pk[r - 8] = m;
    }
    unsigned u0 = cvt_pk_bf16(pk[0], pk[1]), u1 = cvt_pk_bf16(pk[2], pk[3]);
    unsigned u2 = cvt_pk_bf16(pk[4], pk[5]), u3 = cvt_pk_bf16(pk[6], pk[7]);
    perm32swap(u0, u2); perm32swap(u1, u3);
    if ((l31 & 3) == 0)
      *(bf16x8*)(kT + ((size_t)b * 1024 + (p >> 2)) * 16 + hi * 8) =
          pack4(u0, u1, u2, u3);
  }

  // ---- v: pool both tiles, transpose to [c2][m] via LDS ----
  {
    float pv1[16], pv2[16];
    #pragma unroll
    for (int r = 0; r < 16; ++r) {
      float m1 = acc1[r], m2 = acc2[r];
      m1 = fmaxf(m1, __shfl_xor(m1, 1)); m1 = fmaxf(m1, __shfl_xor(m1, 2));
      m2 = fmaxf(m2, __shfl_xor(m2, 1)); m2 = fmaxf(m2, __shfl_xor(m2, 2));
      pv1[r] = m1; pv2[r] = m2;
    }
    if ((l31 & 3) == 0) {
      const int q2l = wid * 8 + (l31 >> 2);
      #pragma unroll
      for (int r = 0; r < 16; ++r) {
        const int c2 = (r & 3) + 8 * (r >> 2) + 4 * hi;
        v_s[c2 * 32 + q2l]        = f2bf(pv1[r]);
        v_s[(32 + c2) * 32 + q2l] = f2bf(pv2[r]);
      }
    }
  }
  __syncthreads();
  {
    const int c2 = t >> 2, off = (t & 3) * 8;
    *(bf16x8*)(vO + ((size_t)b * 64 + c2) * 1024 + blockIdx.x * 32 + off) =
        *(const bf16x8*)&v_s[c2 * 32 + off];
  }
}

// ---------------------------------------------------------------------------
// Kernel 2: flash attention + wo + residual (R3 structure: wave owns 32 q,
// full M). Adds: depth-2 software pipeline (static A/B frag sets),
// s_setprio around compute, XCD-chunked block swizzle, wo staged in LDS.
// ---------------------------------------------------------------------------
#define WOSTRIDE 68   // shorts; 136B row stride, 8B-aligned b64 frag reads

__global__ __launch_bounds__(256) void attn_kernel(
    const short* __restrict__ qT, const short* __restrict__ kT,
    const short* __restrict__ vO, const float* __restrict__ wo,
    const float* __restrict__ x, const float* __restrict__ gamma,
    float* __restrict__ out)
{
  __shared__ short wo_s[128 * WOSTRIDE];   // 17 KB

  const int t = threadIdx.x;
  const int wid = t >> 6, lane = t & 63;
  const int l31 = lane & 31, hi = lane >> 5;

  // XCD-chunked swizzle: XCD k serves batches {2k, 2k+1} (K/V L2-resident)
  const int wg = blockIdx.x;                  // 0..511
  const int swz = (wg & 7) * 64 + (wg >> 3);
  const int b = swz >> 5;
  const int p = (swz & 31) * 128 + wid * 32 + l31;

  // ---- stage wo (128x64 fp32) -> bf16 LDS, padded rows ----
  #pragma unroll
  for (int kk = 0; kk < 8; ++kk) {
    const int idx = t + kk * 256;            // 0..2047 float4
    const int row = idx >> 4, c4 = (idx & 15) << 2;
    const float4 f = *(const float4*)(wo + row * 64 + c4);
    const ull v = ((ull)cvt_pk_bf16(f.z, f.w) << 32) | (ull)cvt_pk_bf16(f.x, f.y);
    *(ull*)&wo_s[row * WOSTRIDE + c4] = v;
  }

  const short* kTb = kT + (size_t)b * 1024 * 16;
  const short* vb  = vO + (size_t)b * 64 * 1024;
  const bf16x8 qf = *(const bf16x8*)(qT + ((size_t)b * 4096 + p) * 16 + hi * 8);

  f32x16 z, o0, o1;
  #pragma unroll
  for (int j = 0; j < 16; ++j) { z[j] = 0.f; o0[j] = 0.f; o1[j] = 0.f; }
  float l = 0.f;

  bf16x8 kfA, v00A, v01A, v10A, v11A;
  bf16x8 kfB, v00B, v01B, v10B, v11B;

#define LOADT(S, M0) do {                                                    \
    const int m0_ = (M0);                                                    \
    kf##S  = *(const bf16x8*)(kTb + (size_t)(m0_ + l31) * 16 + hi * 8);      \
    const size_t r0_ = (size_t)l31 * 1024 + m0_ + hi * 8;                    \
    v00##S = *(const bf16x8*)(vb + r0_);                                     \
    v01##S = *(const bf16x8*)(vb + r0_ + 16);                                \
    v10##S = *(const bf16x8*)(vb + r0_ + 32 * 1024);                         \
    v11##S = *(const bf16x8*)(vb + r0_ + 32 * 1024 + 16); } while (0)

#define COMP(S) do {                                                         \
    f32x16 s = __builtin_amdgcn_mfma_f32_32x32x16_bf16(kf##S, qf, z, 0, 0, 0);\
    float pe[16];                                                            \
    _Pragma("unroll")                                                        \
    for (int j = 0; j < 16; ++j) pe[j] = fexp2(s[j]);                        \
    l += ((pe[0]+pe[1])+(pe[2]+pe[3])) + ((pe[4]+pe[5])+(pe[6]+pe[7]))       \
       + ((pe[8]+pe[9])+(pe[10]+pe[11])) + ((pe[12]+pe[13])+(pe[14]+pe[15]));\
    unsigned a0 = cvt_pk_bf16(pe[0], pe[1]),  a1 = cvt_pk_bf16(pe[2], pe[3]);\
    unsigned a2 = cvt_pk_bf16(pe[4], pe[5]),  a3 = cvt_pk_bf16(pe[6], pe[7]);\
    perm32swap(a0, a2); perm32swap(a1, a3);                                  \
    const bf16x8 P0 = pack4(a0, a1, a2, a3);                                 \
    unsigned c0 = cvt_pk_bf16(pe[8], pe[9]),   c1 = cvt_pk_bf16(pe[10], pe[11]);\
    unsigned c2 = cvt_pk_bf16(pe[12], pe[13]), c3 = cvt_pk_bf16(pe[14], pe[15]);\
    perm32swap(c0, c2); perm32swap(c1, c3);                                  \
    const bf16x8 P1 = pack4(c0, c1, c2, c3);                                 \
    o0 = __builtin_amdgcn_mfma_f32_32x32x16_bf16(v00##S, P0, o0, 0, 0, 0);   \
    o0 = __builtin_amdgcn_mfma_f32_32x32x16_bf16(v01##S, P1, o0, 0, 0, 0);   \
    o1 = __builtin_amdgcn_mfma_f32_32x32x16_bf16(v10##S, P0, o1, 0, 0, 0);   \
    o1 = __builtin_amdgcn_mfma_f32_32x32x16_bf16(v11##S, P1, o1, 0, 0, 0); } while (0)

  LOADT(A, 0);
  #pragma unroll 1
  for (int mt = 0; mt < 32; mt += 2) {
    LOADT(B, (mt + 1) * 32);
    __builtin_amdgcn_s_setprio(1);
    COMP(A);
    __builtin_amdgcn_s_setprio(0);
    const int mn = (mt + 2 < 32) ? (mt + 2) * 32 : 0;   // clamp: no OOB read
    LOADT(A, mn);
    __builtin_amdgcn_s_setprio(1);
    COMP(B);
    __builtin_amdgcn_s_setprio(0);
  }
#undef LOADT
#undef COMP

  __syncthreads();   // wo_s visible

  l += __shfl_xor(l, 32);
  const float inv = 1.0f / l;

  float on[32];
  #pragma unroll
  for (int j = 0; j < 16; ++j) { on[j] = o0[j] * inv; on[16 + j] = o1[j] * inv; }

  bf16x8 ofr[4];
  #pragma unroll
  for (int ck = 0; ck < 4; ++ck) {
    const int base = (ck >> 1) * 16 + (ck & 1) * 8;
    unsigned a0 = cvt_pk_bf16(on[base + 0], on[base + 1]);
    unsigned a1 = cvt_pk_bf16(on[base + 2], on[base + 3]);
    unsigned a2 = cvt_pk_bf16(on[base + 4], on[base + 5]);
    unsigned a3 = cvt_pk_bf16(on[base + 6], on[base + 7]);
    perm32swap(a0, a2); perm32swap(a1, a3);
    ofr[ck] = pack4(a0, a1, a2, a3);
  }

  const int q2 = p >> 2, rr = p & 3;
  const int nsp = ((((q2 >> 5) << 1) | (rr >> 1)) << 6) | (((q2 & 31) << 1) | (rr & 1));
  const float g = gamma[0];
  const float* xb = x + (size_t)b * 128 * 4096 + nsp;
  float* ob = out + (size_t)b * 128 * 4096 + nsp;

  #pragma unroll 1
  for (int cot = 0; cot < 4; ++cot) {
    f32x16 acc;
    #pragma unroll
    for (int j = 0; j < 16; ++j) acc[j] = 0.f;
    #pragma unroll
    for (int ck = 0; ck < 4; ++ck) {
      const short* pw = &wo_s[(cot * 32 + l31) * WOSTRIDE + ck * 16 + hi * 8];
      const bf16x8 wf = pack2ull(*(const ull*)pw, *(const ull*)(pw + 4));
      acc = __builtin_amdgcn_mfma_f32_32x32x16_bf16(wf, ofr[ck], acc, 0, 0, 0);
    }
    #pragma unroll
    for (int r = 0; r < 16; ++r) {
      const int co = cot * 32 + (r & 3) + 8 * (r >> 2) + 4 * hi;
      ob[(size_t)co * 4096] = g * acc[r] + xb[(size_t)co * 4096];
    }
  }
}

extern "C" void kernel_launch(void* const* d_in, const int* in_sizes, int n_in,
                              void* d_out, int out_size, void* d_ws, size_t ws_size,
                              hipStream_t stream) {
  const float* x     = (const float*)d_in[0];
  const float* wq    = (const float*)d_in[1];
  const float* wk    = (const float*)d_in[2];
  const float* wv    = (const float*)d_in[3];
  const float* wo    = (const float*)d_in[4];
  const float* gamma = (const float*)d_in[5];
  float* out = (float*)d_out;

  short* ws = (short*)d_ws;
  short* qT = ws;                 // 16*4096*16
  short* kT = ws + 1048576;       // 16*1024*16
  short* vO = ws + 1310720;       // 16*64*1024

  proj_kernel<<<dim3(32, 16), 256, 0, stream>>>(x, wq, wk, wv, qT, kT, vO);
  attn_kernel<<<dim3(512), 256, 0, stream>>>(qT, kT, vO, wo, x, gamma, out);
}

// Round 7
// 135.166 us; speedup vs baseline: 1.5194x; 1.0204x over previous
//
#include <hip/hip_runtime.h>

// B=16, C=128, H=W=64, N=4096 (zigzag p-space), M=1024, CQ=16, CV=64.
// ws (shorts): qT[16][4096][16] @0, kT[16][1024][16] @1048576,
//              vO[16][64][1024] @1310720.  Total 4.7 MB.

#define LOG2E 1.4426950408889634f

typedef __attribute__((ext_vector_type(8)))  short bf16x8;
typedef __attribute__((ext_vector_type(16))) float f32x16;
typedef unsigned long long ull;

static __device__ __forceinline__ unsigned cvt_pk_bf16(float a, float b) {
  unsigned r;
  asm("v_cvt_pk_bf16_f32 %0, %1, %2" : "=v"(r) : "v"(a), "v"(b));
  return r;
}
static __device__ __forceinline__ void perm32swap(unsigned& a, unsigned& b) {
  asm volatile("v_permlane32_swap_b32 %0, %1" : "+v"(a), "+v"(b));
}
static __device__ __forceinline__ float fexp2(float x) {
  float r; asm("v_exp_f32 %0, %1" : "=v"(r) : "v"(x)); return r;
}
static __device__ __forceinline__ bf16x8 pack4(unsigned u0, unsigned u1,
                                               unsigned u2, unsigned u3) {
  union { bf16x8 v; unsigned u[4]; } r;
  r.u[0] = u0; r.u[1] = u1; r.u[2] = u2; r.u[3] = u3;
  return r.v;
}
static __device__ __forceinline__ bf16x8 pack2ull(ull a, ull b) {
  union { bf16x8 v; ull u[2]; } r;
  r.u[0] = a; r.u[1] = b;
  return r.v;
}
static __device__ __forceinline__ short f2bf(float f) {   // RTNE
  unsigned u = __float_as_uint(f);
  u = (u + 0x7FFFu + ((u >> 16) & 1u)) >> 16;
  return (short)u;
}
// bijective LDS column swizzle: mixes j bits 2-4 and bit 6 into bank-triplet
static __device__ __forceinline__ int swzj(int j) {
  return j ^ ((j >> 2) & 7) ^ (((j >> 6) & 1) << 2);
}
#define FK(V, K) ((K) == 0 ? (V).x : (K) == 1 ? (V).y : (K) == 2 ? (V).z : (V).w)

// ---------------------------------------------------------------------------
// Kernel 1: fused transpose + q/k/v proj + pool.
// Block = 1 pooled row = 128 contiguous n. x staged via coalesced float4
// loads -> swizzled subtiled LDS [16 c-octets][128 j][8 c]; B-frags are then
// single ds_read_b128 (replaces the 64 strided scalar loads that made
// R4/R6 proj ~91 us). Weights in padded LDS (R6). MFMA D[ch][p]=W*x.
// ---------------------------------------------------------------------------
#define WSTRIDE 136   // shorts; 272B row stride, 16B-aligned frag reads

__global__ __launch_bounds__(256) void proj_kernel(
    const float* __restrict__ x, const float* __restrict__ wq,
    const float* __restrict__ wk, const float* __restrict__ wv,
    short* __restrict__ qT, short* __restrict__ kT, short* __restrict__ vO)
{
  __shared__ short x_s[16 * 1024];      // 32 KB: [g][swz(j)][e]
  __shared__ short w_s[96 * WSTRIDE];   // 26 KB: 0-15 wq, 16-31 wk, 32-95 wv
  __shared__ short v_s[64 * 32];        // 4 KB

  const int b = blockIdx.y, t = threadIdx.x;
  const int wid = t >> 6, lane = t & 63;
  const int l31 = lane & 31, hi = lane >> 5;
  const int r = blockIdx.x;             // pooled row 0..31
  const float* xb = x + (size_t)b * 128 * 4096 + r * 128;

  // ---- stage x: 2 rounds x 8 coalesced float4 loads -> swizzled LDS ----
  const int j4  = (t & 31) * 4;
  const int c00 = (t >> 5) * 8;
  #pragma unroll
  for (int R = 0; R < 2; ++R) {
    float4 f[8];
    #pragma unroll
    for (int i = 0; i < 8; ++i)
      f[i] = *(const float4*)(xb + (size_t)(c00 + i + R * 64) * 4096 + j4);
    const int g = (t >> 5) + R * 8;
    #pragma unroll
    for (int k = 0; k < 4; ++k) {
      const bf16x8 frag = pack4(
          cvt_pk_bf16(FK(f[0], k), FK(f[1], k)),
          cvt_pk_bf16(FK(f[2], k), FK(f[3], k)),
          cvt_pk_bf16(FK(f[4], k), FK(f[5], k)),
          cvt_pk_bf16(FK(f[6], k), FK(f[7], k)));
      *(bf16x8*)&x_s[g * 1024 + swzj(j4 + k) * 8] = frag;
    }
  }

  // ---- stage weights -> LDS (coalesced fp32 reads, cvt to bf16) ----
  #pragma unroll
  for (int kk = 0; kk < 12; ++kk) {
    const int idx = t + kk * 256;          // 0..3071
    const int row = idx >> 5, c4 = (idx & 31) << 2;
    const float* src = (row < 16) ? (wq + row * 128 + c4)
                     : (row < 32) ? (wk + (row - 16) * 128 + c4)
                                  : (wv + (row - 32) * 128 + c4);
    const float4 f = *(const float4*)src;
    const ull v = ((ull)cvt_pk_bf16(f.z, f.w) << 32) | (ull)cvt_pk_bf16(f.x, f.y);
    *(ull*)&w_s[row * WSTRIDE + c4] = v;
  }
  __syncthreads();

  // ---- per-lane position (zigzag within the pooled row) ----
  const int p_local = wid * 32 + l31;
  const int q2l = p_local >> 2, rr = p_local & 3;
  const int jl = (rr >> 1) * 64 + q2l * 2 + (rr & 1);   // local n
  const int p = r * 128 + p_local;                      // global zigzag p

  // ---- x B-fragments: one ds_read_b128 per c-octet ----
  bf16x8 xf[8];
  #pragma unroll
  for (int cc = 0; cc < 8; ++cc)
    xf[cc] = *(const bf16x8*)&x_s[(cc * 2 + hi) * 1024 + swzj(jl) * 8];

  // ---- MFMA over K=128 ----
  f32x16 acc0, acc1, acc2;
  #pragma unroll
  for (int j = 0; j < 16; ++j) { acc0[j] = 0.f; acc1[j] = 0.f; acc2[j] = 0.f; }

  #pragma unroll
  for (int cc = 0; cc < 8; ++cc) {
    const int off = cc * 16 + hi * 8;
    const bf16x8 a0 = *(const bf16x8*)&w_s[l31 * WSTRIDE + off];
    const bf16x8 a1 = *(const bf16x8*)&w_s[(32 + l31) * WSTRIDE + off];
    const bf16x8 a2 = *(const bf16x8*)&w_s[(64 + l31) * WSTRIDE + off];
    acc0 = __builtin_amdgcn_mfma_f32_32x32x16_bf16(a0, xf[cc], acc0, 0, 0, 0);
    acc1 = __builtin_amdgcn_mfma_f32_32x32x16_bf16(a1, xf[cc], acc1, 0, 0, 0);
    acc2 = __builtin_amdgcn_mfma_f32_32x32x16_bf16(a2, xf[cc], acc2, 0, 0, 0);
  }

  // ---- q: rows 0..15 (regs 0..7), scaled by log2e, -> B-frag layout ----
  {
    unsigned u0 = cvt_pk_bf16(acc0[0] * LOG2E, acc0[1] * LOG2E);
    unsigned u1 = cvt_pk_bf16(acc0[2] * LOG2E, acc0[3] * LOG2E);
    unsigned u2 = cvt_pk_bf16(acc0[4] * LOG2E, acc0[5] * LOG2E);
    unsigned u3 = cvt_pk_bf16(acc0[6] * LOG2E, acc0[7] * LOG2E);
    perm32swap(u0, u2); perm32swap(u1, u3);
    *(bf16x8*)(qT + ((size_t)b * 4096 + p) * 16 + hi * 8) = pack4(u0, u1, u2, u3);
  }

  // ---- k: rows 16..31 (regs 8..15), pool across lane quads ----
  {
    float pk[8];
    #pragma unroll
    for (int rg = 8; rg < 16; ++rg) {
      float m = acc0[rg];
      m = fmaxf(m, __shfl_xor(m, 1));
      m = fmaxf(m, __shfl_xor(m, 2));
      pk[rg - 8] = m;
    }
    unsigned u0 = cvt_pk_bf16(pk[0], pk[1]), u1 = cvt_pk_bf16(pk[2], pk[3]);
    unsigned u2 = cvt_pk_bf16(pk[4], pk[5]), u3 = cvt_pk_bf16(pk[6], pk[7]);
    perm32swap(u0, u2); perm32swap(u1, u3);
    if ((l31 & 3) == 0)
      *(bf16x8*)(kT + ((size_t)b * 1024 + (p >> 2)) * 16 + hi * 8) =
          pack4(u0, u1, u2, u3);
  }

  // ---- v: pool both tiles, transpose to [c2][m] via LDS ----
  {
    float pv1[16], pv2[16];
    #pragma unroll
    for (int rg = 0; rg < 16; ++rg) {
      float m1 = acc1[rg], m2 = acc2[rg];
      m1 = fmaxf(m1, __shfl_xor(m1, 1)); m1 = fmaxf(m1, __shfl_xor(m1, 2));
      m2 = fmaxf(m2, __shfl_xor(m2, 1)); m2 = fmaxf(m2, __shfl_xor(m2, 2));
      pv1[rg] = m1; pv2[rg] = m2;
    }
    if ((l31 & 3) == 0) {
      const int q2p = wid * 8 + (l31 >> 2);
      #pragma unroll
      for (int rg = 0; rg < 16; ++rg) {
        const int c2 = (rg & 3) + 8 * (rg >> 2) + 4 * hi;
        v_s[c2 * 32 + q2p]        = f2bf(pv1[rg]);
        v_s[(32 + c2) * 32 + q2p] = f2bf(pv2[rg]);
      }
    }
  }
  __syncthreads();
  {
    const int c2 = t >> 2, off = (t & 3) * 8;
    *(bf16x8*)(vO + ((size_t)b * 64 + c2) * 1024 + r * 32 + off) =
        *(const bf16x8*)&v_s[c2 * 32 + off];
  }
}

// ---------------------------------------------------------------------------
// Kernel 2: flash attention + wo + residual, split-M x2 (no atomics).
// 1024 blocks, 4 waves = 2 q-tiles x 2 m-halves. Each wave: R6 depth-2
// pipeline over its 16 M-tiles. Partials combined pairwise via padded LDS
// (fp32, 2 rounds); epilogue split by cot-quadrant between the pair.
// ---------------------------------------------------------------------------
#define WOSTRIDE 68   // shorts; 136B row stride

__global__ __launch_bounds__(256) void attn_kernel(
    const short* __restrict__ qT, const short* __restrict__ kT,
    const short* __restrict__ vO, const float* __restrict__ wo,
    const float* __restrict__ x, const float* __restrict__ gamma,
    float* __restrict__ out)
{
  __shared__ float obuf[2][2][64][18];     // 18 KB, 18-stride = 2-way free
  __shared__ float lbuf[2][2][64];         // 1 KB
  __shared__ short wo_s[128 * WOSTRIDE];   // 17 KB

  const int t = threadIdx.x;
  const int wid = t >> 6, lane = t & 63;
  const int l31 = lane & 31, hi = lane >> 5;
  const int qhalf = wid >> 1, mhalf = wid & 1;

  // XCD-chunked swizzle: XCD k serves batches {2k, 2k+1}
  const int wg = blockIdx.x;                  // 0..1023
  const int sw = (wg & 7) * 128 + (wg >> 3);
  const int b = sw >> 6;
  const int p = (sw & 63) * 64 + qhalf * 32 + l31;

  // ---- stage wo (128x64 fp32) -> bf16 LDS, padded rows ----
  #pragma unroll
  for (int kk = 0; kk < 8; ++kk) {
    const int idx = t + kk * 256;            // 0..2047 float4
    const int row = idx >> 4, c4 = (idx & 15) << 2;
    const float4 f = *(const float4*)(wo + row * 64 + c4);
    const ull v = ((ull)cvt_pk_bf16(f.z, f.w) << 32) | (ull)cvt_pk_bf16(f.x, f.y);
    *(ull*)&wo_s[row * WOSTRIDE + c4] = v;
  }

  const short* kTb = kT + (size_t)b * 1024 * 16;
  const short* vb  = vO + (size_t)b * 64 * 1024;
  const bf16x8 qf = *(const bf16x8*)(qT + ((size_t)b * 4096 + p) * 16 + hi * 8);

  f32x16 z, o0, o1;
  #pragma unroll
  for (int j = 0; j < 16; ++j) { z[j] = 0.f; o0[j] = 0.f; o1[j] = 0.f; }
  float l = 0.f;

  const int mbase = mhalf * 512;

  bf16x8 kfA, v00A, v01A, v10A, v11A;
  bf16x8 kfB, v00B, v01B, v10B, v11B;

#define LOADT(S, M0) do {                                                    \
    const int m0_ = (M0);                                                    \
    kf##S  = *(const bf16x8*)(kTb + (size_t)(m0_ + l31) * 16 + hi * 8);      \
    const size_t r0_ = (size_t)l31 * 1024 + m0_ + hi * 8;                    \
    v00##S = *(const bf16x8*)(vb + r0_);                                     \
    v01##S = *(const bf16x8*)(vb + r0_ + 16);                                \
    v10##S = *(const bf16x8*)(vb + r0_ + 32 * 1024);                         \
    v11##S = *(const bf16x8*)(vb + r0_ + 32 * 1024 + 16); } while (0)

#define COMP(S) do {                                                         \
    f32x16 s = __builtin_amdgcn_mfma_f32_32x32x16_bf16(kf##S, qf, z, 0, 0, 0);\
    float pe[16];                                                            \
    _Pragma("unroll")                                                        \
    for (int j = 0; j < 16; ++j) pe[j] = fexp2(s[j]);                        \
    l += ((pe[0]+pe[1])+(pe[2]+pe[3])) + ((pe[4]+pe[5])+(pe[6]+pe[7]))       \
       + ((pe[8]+pe[9])+(pe[10]+pe[11])) + ((pe[12]+pe[13])+(pe[14]+pe[15]));\
    unsigned a0 = cvt_pk_bf16(pe[0], pe[1]),  a1 = cvt_pk_bf16(pe[2], pe[3]);\
    unsigned a2 = cvt_pk_bf16(pe[4], pe[5]),  a3 = cvt_pk_bf16(pe[6], pe[7]);\
    perm32swap(a0, a2); perm32swap(a1, a3);                                  \
    const bf16x8 P0 = pack4(a0, a1, a2, a3);                                 \
    unsigned c0 = cvt_pk_bf16(pe[8], pe[9]),   c1 = cvt_pk_bf16(pe[10], pe[11]);\
    unsigned c2 = cvt_pk_bf16(pe[12], pe[13]), c3 = cvt_pk_bf16(pe[14], pe[15]);\
    perm32swap(c0, c2); perm32swap(c1, c3);                                  \
    const bf16x8 P1 = pack4(c0, c1, c2, c3);                                 \
    o0 = __builtin_amdgcn_mfma_f32_32x32x16_bf16(v00##S, P0, o0, 0, 0, 0);   \
    o0 = __builtin_amdgcn_mfma_f32_32x32x16_bf16(v01##S, P1, o0, 0, 0, 0);   \
    o1 = __builtin_amdgcn_mfma_f32_32x32x16_bf16(v10##S, P0, o1, 0, 0, 0);   \
    o1 = __builtin_amdgcn_mfma_f32_32x32x16_bf16(v11##S, P1, o1, 0, 0, 0); } while (0)

  LOADT(A, mbase);
  #pragma unroll 1
  for (int mt = 0; mt < 16; mt += 2) {
    LOADT(B, mbase + (mt + 1) * 32);
    __builtin_amdgcn_s_setprio(1);
    COMP(A);
    __builtin_amdgcn_s_setprio(0);
    const int mn = (mt + 2 < 16) ? mbase + (mt + 2) * 32 : mbase;  // clamp
    LOADT(A, mn);
    __builtin_amdgcn_s_setprio(1);
    COMP(B);
    __builtin_amdgcn_s_setprio(0);
  }
#undef LOADT
#undef COMP

  // ---- pairwise combine (fp32, 2 rounds, no atomics) ----
  l += __shfl_xor(l, 32);
  float* mybuf = &obuf[qhalf][mhalf][lane][0];
  const float* pbuf = &obuf[qhalf][mhalf ^ 1][lane][0];

  #pragma unroll
  for (int j = 0; j < 16; ++j) mybuf[j] = o0[j];
  lbuf[qhalf][mhalf][lane] = l;
  __syncthreads();
  #pragma unroll
  for (int j = 0; j < 16; ++j) o0[j] += pbuf[j];
  l += lbuf[qhalf][mhalf ^ 1][lane];
  __syncthreads();
  #pragma unroll
  for (int j = 0; j < 16; ++j) mybuf[j] = o1[j];
  __syncthreads();
  #pragma unroll
  for (int j = 0; j < 16; ++j) o1[j] += pbuf[j];

  const float inv = 1.0f / l;

  float on[32];
  #pragma unroll
  for (int j = 0; j < 16; ++j) { on[j] = o0[j] * inv; on[16 + j] = o1[j] * inv; }

  bf16x8 ofr[4];
  #pragma unroll
  for (int ck = 0; ck < 4; ++ck) {
    const int base = (ck >> 1) * 16 + (ck & 1) * 8;
    unsigned a0 = cvt_pk_bf16(on[base + 0], on[base + 1]);
    unsigned a1 = cvt_pk_bf16(on[base + 2], on[base + 3]);
    unsigned a2 = cvt_pk_bf16(on[base + 4], on[base + 5]);
    unsigned a3 = cvt_pk_bf16(on[base + 6], on[base + 7]);
    perm32swap(a0, a2); perm32swap(a1, a3);
    ofr[ck] = pack4(a0, a1, a2, a3);
  }

  const int q2 = p >> 2, rr = p & 3;
  const int nsp = ((((q2 >> 5) << 1) | (rr >> 1)) << 6) | (((q2 & 31) << 1) | (rr & 1));
  const float g = gamma[0];
  const float* xb = x + (size_t)b * 128 * 4096 + nsp;
  float* ob = out + (size_t)b * 128 * 4096 + nsp;

  // ---- epilogue: this wave handles cot quadrants {mhalf*2, mhalf*2+1} ----
  #pragma unroll 1
  for (int ci = 0; ci < 2; ++ci) {
    const int cot = mhalf * 2 + ci;
    f32x16 acc;
    #pragma unroll
    for (int j = 0; j < 16; ++j) acc[j] = 0.f;
    #pragma unroll
    for (int ck = 0; ck < 4; ++ck) {
      const short* pw = &wo_s[(cot * 32 + l31) * WOSTRIDE + ck * 16 + hi * 8];
      const bf16x8 wf = pack2ull(*(const ull*)pw, *(const ull*)(pw + 4));
      acc = __builtin_amdgcn_mfma_f32_32x32x16_bf16(wf, ofr[ck], acc, 0, 0, 0);
    }
    #pragma unroll
    for (int rg = 0; rg < 16; ++rg) {
      const int co = cot * 32 + (rg & 3) + 8 * (rg >> 2) + 4 * hi;
      ob[(size_t)co * 4096] = g * acc[rg] + xb[(size_t)co * 4096];
    }
  }
}

extern "C" void kernel_launch(void* const* d_in, const int* in_sizes, int n_in,
                              void* d_out, int out_size, void* d_ws, size_t ws_size,
                              hipStream_t stream) {
  const float* x     = (const float*)d_in[0];
  const float* wq    = (const float*)d_in[1];
  const float* wk    = (const float*)d_in[2];
  const float* wv    = (const float*)d_in[3];
  const float* wo    = (const float*)d_in[4];
  const float* gamma = (const float*)d_in[5];
  float* out = (float*)d_out;

  short* ws = (short*)d_ws;
  short* qT = ws;                 // 16*4096*16
  short* kT = ws + 1048576;       // 16*1024*16
  short* vO = ws + 1310720;       // 16*64*1024

  proj_kernel<<<dim3(32, 16), 256, 0, stream>>>(x, wq, wk, wv, qT, kT, vO);
  attn_kernel<<<dim3(1024), 256, 0, stream>>>(qT, kT, vO, wo, x, gamma, out);
}

// Round 8
// 119.985 us; speedup vs baseline: 1.7116x; 1.1265x over previous
//
#include <hip/hip_runtime.h>

// B=16, C=128, H=W=64, N=4096 (zigzag p-space), M=1024, CQ=16, CV=64.
// ws (shorts): qT[16][4096][16] @0, kT[16][1024][16] @1048576,
//              vT[16][32 mt][2 ks][64 c2][16 mm] @1310720.  Total 4.7 MB.
// vT layout: every PV A-fragment load is a lane-contiguous 1KB transaction
// (R7's [c2][1024] layout hit 32 half-used 64B lines per instruction).

#define LOG2E 1.4426950408889634f

typedef __attribute__((ext_vector_type(8)))  short bf16x8;
typedef __attribute__((ext_vector_type(16))) float f32x16;
typedef unsigned long long ull;

static __device__ __forceinline__ unsigned cvt_pk_bf16(float a, float b) {
  unsigned r;
  asm("v_cvt_pk_bf16_f32 %0, %1, %2" : "=v"(r) : "v"(a), "v"(b));
  return r;
}
static __device__ __forceinline__ void perm32swap(unsigned& a, unsigned& b) {
  asm volatile("v_permlane32_swap_b32 %0, %1" : "+v"(a), "+v"(b));
}
static __device__ __forceinline__ float fexp2(float x) {
  float r; asm("v_exp_f32 %0, %1" : "=v"(r) : "v"(x)); return r;
}
static __device__ __forceinline__ bf16x8 pack4(unsigned u0, unsigned u1,
                                               unsigned u2, unsigned u3) {
  union { bf16x8 v; unsigned u[4]; } r;
  r.u[0] = u0; r.u[1] = u1; r.u[2] = u2; r.u[3] = u3;
  return r.v;
}
static __device__ __forceinline__ bf16x8 pack2ull(ull a, ull b) {
  union { bf16x8 v; ull u[2]; } r;
  r.u[0] = a; r.u[1] = b;
  return r.v;
}
static __device__ __forceinline__ short f2bf(float f) {   // RTNE
  unsigned u = __float_as_uint(f);
  u = (u + 0x7FFFu + ((u >> 16) & 1u)) >> 16;
  return (short)u;
}
// bijective LDS column swizzle: mixes j bits 2-4 and bit 6 into bank-triplet
static __device__ __forceinline__ int swzj(int j) {
  return j ^ ((j >> 2) & 7) ^ (((j >> 6) & 1) << 2);
}
#define FK(V, K) ((K) == 0 ? (V).x : (K) == 1 ? (V).y : (K) == 2 ? (V).z : (V).w)

// ---------------------------------------------------------------------------
// Kernel 1: fused transpose + q/k/v proj + pool (R7 structure; only the
// v_s / vT indexing changed for the new V tile layout).
// ---------------------------------------------------------------------------
#define WSTRIDE 136   // shorts; 272B row stride, 16B-aligned frag reads

__global__ __launch_bounds__(256) void proj_kernel(
    const float* __restrict__ x, const float* __restrict__ wq,
    const float* __restrict__ wk, const float* __restrict__ wv,
    short* __restrict__ qT, short* __restrict__ kT, short* __restrict__ vT)
{
  __shared__ short x_s[16 * 1024];      // 32 KB: [g][swz(j)][e]
  __shared__ short w_s[96 * WSTRIDE];   // 26 KB: 0-15 wq, 16-31 wk, 32-95 wv
  __shared__ short v_s[2048];           // 4 KB: [ks][c2][16 mm]

  const int b = blockIdx.y, t = threadIdx.x;
  const int wid = t >> 6, lane = t & 63;
  const int l31 = lane & 31, hi = lane >> 5;
  const int r = blockIdx.x;             // pooled row 0..31 == m-tile index
  const float* xb = x + (size_t)b * 128 * 4096 + r * 128;

  // ---- stage x: 2 rounds x 8 coalesced float4 loads -> swizzled LDS ----
  const int j4  = (t & 31) * 4;
  const int c00 = (t >> 5) * 8;
  #pragma unroll
  for (int R = 0; R < 2; ++R) {
    float4 f[8];
    #pragma unroll
    for (int i = 0; i < 8; ++i)
      f[i] = *(const float4*)(xb + (size_t)(c00 + i + R * 64) * 4096 + j4);
    const int g = (t >> 5) + R * 8;
    #pragma unroll
    for (int k = 0; k < 4; ++k) {
      const bf16x8 frag = pack4(
          cvt_pk_bf16(FK(f[0], k), FK(f[1], k)),
          cvt_pk_bf16(FK(f[2], k), FK(f[3], k)),
          cvt_pk_bf16(FK(f[4], k), FK(f[5], k)),
          cvt_pk_bf16(FK(f[6], k), FK(f[7], k)));
      *(bf16x8*)&x_s[g * 1024 + swzj(j4 + k) * 8] = frag;
    }
  }

  // ---- stage weights -> LDS (coalesced fp32 reads, cvt to bf16) ----
  #pragma unroll
  for (int kk = 0; kk < 12; ++kk) {
    const int idx = t + kk * 256;          // 0..3071
    const int row = idx >> 5, c4 = (idx & 31) << 2;
    const float* src = (row < 16) ? (wq + row * 128 + c4)
                     : (row < 32) ? (wk + (row - 16) * 128 + c4)
                                  : (wv + (row - 32) * 128 + c4);
    const float4 f = *(const float4*)src;
    const ull v = ((ull)cvt_pk_bf16(f.z, f.w) << 32) | (ull)cvt_pk_bf16(f.x, f.y);
    *(ull*)&w_s[row * WSTRIDE + c4] = v;
  }
  __syncthreads();

  // ---- per-lane position (zigzag within the pooled row) ----
  const int p_local = wid * 32 + l31;
  const int q2l = p_local >> 2, rr = p_local & 3;
  const int jl = (rr >> 1) * 64 + q2l * 2 + (rr & 1);   // local n
  const int p = r * 128 + p_local;                      // global zigzag p

  // ---- x B-fragments: one ds_read_b128 per c-octet ----
  bf16x8 xf[8];
  #pragma unroll
  for (int cc = 0; cc < 8; ++cc)
    xf[cc] = *(const bf16x8*)&x_s[(cc * 2 + hi) * 1024 + swzj(jl) * 8];

  // ---- MFMA over K=128 ----
  f32x16 acc0, acc1, acc2;
  #pragma unroll
  for (int j = 0; j < 16; ++j) { acc0[j] = 0.f; acc1[j] = 0.f; acc2[j] = 0.f; }

  #pragma unroll
  for (int cc = 0; cc < 8; ++cc) {
    const int off = cc * 16 + hi * 8;
    const bf16x8 a0 = *(const bf16x8*)&w_s[l31 * WSTRIDE + off];
    const bf16x8 a1 = *(const bf16x8*)&w_s[(32 + l31) * WSTRIDE + off];
    const bf16x8 a2 = *(const bf16x8*)&w_s[(64 + l31) * WSTRIDE + off];
    acc0 = __builtin_amdgcn_mfma_f32_32x32x16_bf16(a0, xf[cc], acc0, 0, 0, 0);
    acc1 = __builtin_amdgcn_mfma_f32_32x32x16_bf16(a1, xf[cc], acc1, 0, 0, 0);
    acc2 = __builtin_amdgcn_mfma_f32_32x32x16_bf16(a2, xf[cc], acc2, 0, 0, 0);
  }

  // ---- q: rows 0..15 (regs 0..7), scaled by log2e, -> B-frag layout ----
  {
    unsigned u0 = cvt_pk_bf16(acc0[0] * LOG2E, acc0[1] * LOG2E);
    unsigned u1 = cvt_pk_bf16(acc0[2] * LOG2E, acc0[3] * LOG2E);
    unsigned u2 = cvt_pk_bf16(acc0[4] * LOG2E, acc0[5] * LOG2E);
    unsigned u3 = cvt_pk_bf16(acc0[6] * LOG2E, acc0[7] * LOG2E);
    perm32swap(u0, u2); perm32swap(u1, u3);
    *(bf16x8*)(qT + ((size_t)b * 4096 + p) * 16 + hi * 8) = pack4(u0, u1, u2, u3);
  }

  // ---- k: rows 16..31 (regs 8..15), pool across lane quads ----
  {
    float pk[8];
    #pragma unroll
    for (int rg = 8; rg < 16; ++rg) {
      float m = acc0[rg];
      m = fmaxf(m, __shfl_xor(m, 1));
      m = fmaxf(m, __shfl_xor(m, 2));
      pk[rg - 8] = m;
    }
    unsigned u0 = cvt_pk_bf16(pk[0], pk[1]), u1 = cvt_pk_bf16(pk[2], pk[3]);
    unsigned u2 = cvt_pk_bf16(pk[4], pk[5]), u3 = cvt_pk_bf16(pk[6], pk[7]);
    perm32swap(u0, u2); perm32swap(u1, u3);
    if ((l31 & 3) == 0)
      *(bf16x8*)(kT + ((size_t)b * 1024 + (p >> 2)) * 16 + hi * 8) =
          pack4(u0, u1, u2, u3);
  }

  // ---- v: pool both tiles -> v_s[ks][c2][16 mm] ----
  {
    float pv1[16], pv2[16];
    #pragma unroll
    for (int rg = 0; rg < 16; ++rg) {
      float m1 = acc1[rg], m2 = acc2[rg];
      m1 = fmaxf(m1, __shfl_xor(m1, 1)); m1 = fmaxf(m1, __shfl_xor(m1, 2));
      m2 = fmaxf(m2, __shfl_xor(m2, 1)); m2 = fmaxf(m2, __shfl_xor(m2, 2));
      pv1[rg] = m1; pv2[rg] = m2;
    }
    if ((l31 & 3) == 0) {
      const int q2p = wid * 8 + (l31 >> 2);      // m within tile, 0..31
      const int ks = q2p >> 4, mm = q2p & 15;
      #pragma unroll
      for (int rg = 0; rg < 16; ++rg) {
        const int c2 = (rg & 3) + 8 * (rg >> 2) + 4 * hi;
        v_s[ks * 1024 + c2 * 16 + mm]        = f2bf(pv1[rg]);
        v_s[ks * 1024 + (32 + c2) * 16 + mm] = f2bf(pv2[rg]);
      }
    }
  }
  __syncthreads();
  // linear b128 LDS read -> fully contiguous 4KB global store (tile mt = r)
  *(bf16x8*)(vT + (size_t)b * 65536 + r * 2048 + t * 8) =
      *(const bf16x8*)&v_s[t * 8];
}

// ---------------------------------------------------------------------------
// Kernel 2: flash attention + wo + residual, split-M x2 (R7 structure).
// Only change: V loads use the [mt][ks][c2][16] tile layout -- each A-frag
// load is one lane-contiguous 1KB transaction group.
// ---------------------------------------------------------------------------
#define WOSTRIDE 68   // shorts; 136B row stride

__global__ __launch_bounds__(256) void attn_kernel(
    const short* __restrict__ qT, const short* __restrict__ kT,
    const short* __restrict__ vT, const float* __restrict__ wo,
    const float* __restrict__ x, const float* __restrict__ gamma,
    float* __restrict__ out)
{
  __shared__ float obuf[2][2][64][18];     // 18 KB, 18-stride = 2-way free
  __shared__ float lbuf[2][2][64];         // 1 KB
  __shared__ short wo_s[128 * WOSTRIDE];   // 17 KB

  const int t = threadIdx.x;
  const int wid = t >> 6, lane = t & 63;
  const int l31 = lane & 31, hi = lane >> 5;
  const int qhalf = wid >> 1, mhalf = wid & 1;

  // XCD-chunked swizzle: XCD k serves batches {2k, 2k+1}
  const int wg = blockIdx.x;                  // 0..1023
  const int sw = (wg & 7) * 128 + (wg >> 3);
  const int b = sw >> 6;
  const int p = (sw & 63) * 64 + qhalf * 32 + l31;

  // ---- stage wo (128x64 fp32) -> bf16 LDS, padded rows ----
  #pragma unroll
  for (int kk = 0; kk < 8; ++kk) {
    const int idx = t + kk * 256;            // 0..2047 float4
    const int row = idx >> 4, c4 = (idx & 15) << 2;
    const float4 f = *(const float4*)(wo + row * 64 + c4);
    const ull v = ((ull)cvt_pk_bf16(f.z, f.w) << 32) | (ull)cvt_pk_bf16(f.x, f.y);
    *(ull*)&wo_s[row * WOSTRIDE + c4] = v;
  }

  const short* kTb = kT + (size_t)b * 1024 * 16;
  const short* vb  = vT + (size_t)b * 65536;
  const bf16x8 qf = *(const bf16x8*)(qT + ((size_t)b * 4096 + p) * 16 + hi * 8);

  f32x16 z, o0, o1;
  #pragma unroll
  for (int j = 0; j < 16; ++j) { z[j] = 0.f; o0[j] = 0.f; o1[j] = 0.f; }
  float l = 0.f;

  const int mtbase = mhalf * 16;

  bf16x8 kfA, v00A, v01A, v10A, v11A;
  bf16x8 kfB, v00B, v01B, v10B, v11B;

#define LOADT(S, MT) do {                                                    \
    const int mt_ = (MT);                                                    \
    kf##S  = *(const bf16x8*)(kTb + (size_t)(mt_ * 32 + l31) * 16 + hi * 8); \
    const short* tb_ = vb + (size_t)mt_ * 2048 + l31 * 16 + hi * 8;          \
    v00##S = *(const bf16x8*)(tb_);                                          \
    v10##S = *(const bf16x8*)(tb_ + 512);                                    \
    v01##S = *(const bf16x8*)(tb_ + 1024);                                   \
    v11##S = *(const bf16x8*)(tb_ + 1536); } while (0)

#define COMP(S) do {                                                         \
    f32x16 s = __builtin_amdgcn_mfma_f32_32x32x16_bf16(kf##S, qf, z, 0, 0, 0);\
    float pe[16];                                                            \
    _Pragma("unroll")                                                        \
    for (int j = 0; j < 16; ++j) pe[j] = fexp2(s[j]);                        \
    l += ((pe[0]+pe[1])+(pe[2]+pe[3])) + ((pe[4]+pe[5])+(pe[6]+pe[7]))       \
       + ((pe[8]+pe[9])+(pe[10]+pe[11])) + ((pe[12]+pe[13])+(pe[14]+pe[15]));\
    unsigned a0 = cvt_pk_bf16(pe[0], pe[1]),  a1 = cvt_pk_bf16(pe[2], pe[3]);\
    unsigned a2 = cvt_pk_bf16(pe[4], pe[5]),  a3 = cvt_pk_bf16(pe[6], pe[7]);\
    perm32swap(a0, a2); perm32swap(a1, a3);                                  \
    const bf16x8 P0 = pack4(a0, a1, a2, a3);                                 \
    unsigned c0 = cvt_pk_bf16(pe[8], pe[9]),   c1 = cvt_pk_bf16(pe[10], pe[11]);\
    unsigned c2 = cvt_pk_bf16(pe[12], pe[13]), c3 = cvt_pk_bf16(pe[14], pe[15]);\
    perm32swap(c0, c2); perm32swap(c1, c3);                                  \
    const bf16x8 P1 = pack4(c0, c1, c2, c3);                                 \
    o0 = __builtin_amdgcn_mfma_f32_32x32x16_bf16(v00##S, P0, o0, 0, 0, 0);   \
    o0 = __builtin_amdgcn_mfma_f32_32x32x16_bf16(v01##S, P1, o0, 0, 0, 0);   \
    o1 = __builtin_amdgcn_mfma_f32_32x32x16_bf16(v10##S, P0, o1, 0, 0, 0);   \
    o1 = __builtin_amdgcn_mfma_f32_32x32x16_bf16(v11##S, P1, o1, 0, 0, 0); } while (0)

  LOADT(A, mtbase);
  #pragma unroll 1
  for (int mt = 0; mt < 16; mt += 2) {
    LOADT(B, mtbase + mt + 1);
    __builtin_amdgcn_s_setprio(1);
    COMP(A);
    __builtin_amdgcn_s_setprio(0);
    const int mn = (mt + 2 < 16) ? mtbase + mt + 2 : mtbase;  // clamp
    LOADT(A, mn);
    __builtin_amdgcn_s_setprio(1);
    COMP(B);
    __builtin_amdgcn_s_setprio(0);
  }
#undef LOADT
#undef COMP

  // ---- pairwise combine (fp32, 2 rounds, no atomics) ----
  l += __shfl_xor(l, 32);
  float* mybuf = &obuf[qhalf][mhalf][lane][0];
  const float* pbuf = &obuf[qhalf][mhalf ^ 1][lane][0];

  #pragma unroll
  for (int j = 0; j < 16; ++j) mybuf[j] = o0[j];
  lbuf[qhalf][mhalf][lane] = l;
  __syncthreads();
  #pragma unroll
  for (int j = 0; j < 16; ++j) o0[j] += pbuf[j];
  l += lbuf[qhalf][mhalf ^ 1][lane];
  __syncthreads();
  #pragma unroll
  for (int j = 0; j < 16; ++j) mybuf[j] = o1[j];
  __syncthreads();
  #pragma unroll
  for (int j = 0; j < 16; ++j) o1[j] += pbuf[j];

  const float inv = 1.0f / l;

  float on[32];
  #pragma unroll
  for (int j = 0; j < 16; ++j) { on[j] = o0[j] * inv; on[16 + j] = o1[j] * inv; }

  bf16x8 ofr[4];
  #pragma unroll
  for (int ck = 0; ck < 4; ++ck) {
    const int base = (ck >> 1) * 16 + (ck & 1) * 8;
    unsigned a0 = cvt_pk_bf16(on[base + 0], on[base + 1]);
    unsigned a1 = cvt_pk_bf16(on[base + 2], on[base + 3]);
    unsigned a2 = cvt_pk_bf16(on[base + 4], on[base + 5]);
    unsigned a3 = cvt_pk_bf16(on[base + 6], on[base + 7]);
    perm32swap(a0, a2); perm32swap(a1, a3);
    ofr[ck] = pack4(a0, a1, a2, a3);
  }

  const int q2 = p >> 2, rr = p & 3;
  const int nsp = ((((q2 >> 5) << 1) | (rr >> 1)) << 6) | (((q2 & 31) << 1) | (rr & 1));
  const float g = gamma[0];
  const float* xb = x + (size_t)b * 128 * 4096 + nsp;
  float* ob = out + (size_t)b * 128 * 4096 + nsp;

  // ---- epilogue: this wave handles cot quadrants {mhalf*2, mhalf*2+1} ----
  #pragma unroll 1
  for (int ci = 0; ci < 2; ++ci) {
    const int cot = mhalf * 2 + ci;
    f32x16 acc;
    #pragma unroll
    for (int j = 0; j < 16; ++j) acc[j] = 0.f;
    #pragma unroll
    for (int ck = 0; ck < 4; ++ck) {
      const short* pw = &wo_s[(cot * 32 + l31) * WOSTRIDE + ck * 16 + hi * 8];
      const bf16x8 wf = pack2ull(*(const ull*)pw, *(const ull*)(pw + 4));
      acc = __builtin_amdgcn_mfma_f32_32x32x16_bf16(wf, ofr[ck], acc, 0, 0, 0);
    }
    #pragma unroll
    for (int rg = 0; rg < 16; ++rg) {
      const int co = cot * 32 + (rg & 3) + 8 * (rg >> 2) + 4 * hi;
      ob[(size_t)co * 4096] = g * acc[rg] + xb[(size_t)co * 4096];
    }
  }
}

extern "C" void kernel_launch(void* const* d_in, const int* in_sizes, int n_in,
                              void* d_out, int out_size, void* d_ws, size_t ws_size,
                              hipStream_t stream) {
  const float* x     = (const float*)d_in[0];
  const float* wq    = (const float*)d_in[1];
  const float* wk    = (const float*)d_in[2];
  const float* wv    = (const float*)d_in[3];
  const float* wo    = (const float*)d_in[4];
  const float* gamma = (const float*)d_in[5];
  float* out = (float*)d_out;

  short* ws = (short*)d_ws;
  short* qT = ws;                 // 16*4096*16
  short* kT = ws + 1048576;       // 16*1024*16
  short* vT = ws + 1310720;       // 16*32*2048

  proj_kernel<<<dim3(32, 16), 256, 0, stream>>>(x, wq, wk, wv, qT, kT, vT);
  attn_kernel<<<dim3(1024), 256, 0, stream>>>(qT, kT, vT, wo, x, gamma, out);
}